// Round 7
// baseline (33.765 us; speedup 1.0000x reference)
//
#include <hip/hip_runtime.h>
#include <hip/hip_bf16.h>

// ResidualRotationWarpLayer: out[b,y,x,c] = bilinear(images[b], H_b warp of (x,y))
// H_b = diag(fx,fy,1) * R(q) * diag(fx,fy,1)^-1
// B=32, H=512, W=512, C=3, fp32.
//
// R7: fuse the (x0, x0+1) corner pair into one 6-float contiguous load
// (dwordx4 + dwordx2, align-4) -> VMEM insts/thread 24 -> 8. Edge cases via
// cndmask selects: x0==-1 re-selects pixel 0 for p01; base clamp keeps the
// 24B read inside the image buffer (exact-page-multiple allocation).

#define IMG_H 512
#define IMG_W 512
#define IMG_C 3
#define NB    32

typedef float f32x4  __attribute__((ext_vector_type(4)));
typedef float f32x4u __attribute__((ext_vector_type(4), aligned(4)));
typedef float f32x2u __attribute__((ext_vector_type(2), aligned(4)));

__global__ __launch_bounds__(256) void warp_kernel(
    const float* __restrict__ images,
    const float* __restrict__ focal,
    const float* __restrict__ q,
    float* __restrict__ out)
{
    // --- XCD-aware remap: 16384 blocks = 8 XCDs * 2048; each XCD owns 4 images
    const unsigned bid  = blockIdx.x;
    const unsigned xcd  = bid & 7u;
    const unsigned slot = bid >> 3;
    const unsigned virt = xcd * 2048u + slot;
    const int b = (int)(virt >> 9);      // 512 rows per image
    const int y = (int)(virt & 511u);

    const int tid = threadIdx.x;

    __shared__ float sH[9];
    __shared__ float s_out[IMG_W * IMG_C];   // 1536 floats = 6 KB

    if (tid == 0) {
        // replicate reference op order for numerics
        float q0 = q[0], q1 = q[1], q2 = q[2], q3 = q[3];
        float s = sqrtf(2.0f / (q0*q0 + q1*q1 + q2*q2 + q3*q3));
        q0 *= s; q1 *= s; q2 *= s; q3 *= s;
        float R00 = 1.0f - q2*q2 - q3*q3;
        float R01 = q1*q2 - q3*q0;
        float R02 = q1*q3 + q2*q0;
        float R10 = q1*q2 + q3*q0;
        float R11 = 1.0f - q1*q1 - q3*q3;
        float R12 = q2*q3 - q1*q0;
        float R20 = q1*q3 - q2*q0;
        float R21 = q2*q3 + q1*q0;
        float R22 = 1.0f - q1*q1 - q2*q2;
        float d0 = focal[b*2 + 0];
        float d1 = focal[b*2 + 1];
        sH[0] = (R00*d0)/d0; sH[1] = (R01*d0)/d1; sH[2] = (R02*d0);
        sH[3] = (R10*d1)/d0; sH[4] = (R11*d1)/d1; sH[5] = (R12*d1);
        sH[6] = R20/d0;      sH[7] = R21/d1;      sH[8] = R22;
    }
    __syncthreads();

    const float h0 = sH[0], h1 = sH[1], h2 = sH[2];
    const float h3 = sH[3], h4 = sH[4], h5 = sH[5];
    const float h6 = sH[6], h7 = sH[7], h8 = sH[8];

    const float ys = (float)y - 256.0f;
    // row-constant parts of the projective transform
    const float r1 = h1*ys + h2;
    const float r4 = h4*ys + h5;
    const float r7 = h7*ys + h8;

    const float* __restrict__ img_b = images + (unsigned)b * (IMG_H * IMG_W * IMG_C);
    const unsigned LIMIT = (unsigned)(IMG_H * IMG_W - 2);   // last safe 2-pixel base

    // ---- per-pixel sampling: one 6-float pair-load per corner row ----
    #define SAMPLE(PX, A0, A1, A2) do {                                        \
        const float xs = (float)(PX) - 256.0f;                                 \
        float p0 = h0*xs + r1;                                                 \
        float p1 = h3*xs + r4;                                                 \
        float p2 = h6*xs + r7;                                                 \
        float xw = p0 / p2 + 256.0f;                                           \
        float yw = p1 / p2 + 256.0f;                                           \
        float x0f = floorf(xw), y0f = floorf(yw);                              \
        float wx = xw - x0f,   wy = yw - y0f;                                  \
        int x0 = (int)x0f, y0i = (int)y0f;                                     \
        int x1 = x0 + 1,  y1i = y0i + 1;                                       \
        bool vx0 = (x0 >= 0) & (x0 <= IMG_W-1);                                \
        bool vx1 = (x1 >= 0) & (x1 <= IMG_W-1);                                \
        bool vy0 = (y0i >= 0) & (y0i <= IMG_H-1);                              \
        bool vy1 = (y1i >= 0) & (y1i <= IMG_H-1);                              \
        bool xn  = (x0 < 0);                                                   \
        unsigned xc0 = (unsigned)min(max(x0, 0), IMG_W-1);                     \
        unsigned yc0 = (unsigned)min(max(y0i, 0), IMG_H-1);                    \
        unsigned yc1 = (unsigned)min(max(y1i, 0), IMG_H-1);                    \
        unsigned idxA = yc0 * IMG_W + xc0;                                     \
        unsigned idxB = yc1 * IMG_W + xc0;                                     \
        bool shA = idxA > LIMIT;                                               \
        bool shB = idxB > LIMIT;                                               \
        const float* bpA = img_b + 3u * (shA ? LIMIT : idxA);                  \
        const float* bpB = img_b + 3u * (shB ? LIMIT : idxB);                  \
        f32x4u vA0 = *reinterpret_cast<const f32x4u*>(bpA);                    \
        f32x2u vA1 = *reinterpret_cast<const f32x2u*>(bpA + 4);                \
        f32x4u vB0 = *reinterpret_cast<const f32x4u*>(bpB);                    \
        f32x2u vB1 = *reinterpret_cast<const f32x2u*>(bpB + 4);                \
        float a00 = shA ? vA0.w : vA0.x;                                       \
        float a01 = shA ? vA1.x : vA0.y;                                       \
        float a02 = shA ? vA1.y : vA0.z;                                       \
        float b00 = xn ? vA0.x : vA0.w;                                        \
        float b01 = xn ? vA0.y : vA1.x;                                        \
        float b02 = xn ? vA0.z : vA1.y;                                        \
        float c00 = shB ? vB0.w : vB0.x;                                       \
        float c01 = shB ? vB1.x : vB0.y;                                       \
        float c02 = shB ? vB1.y : vB0.z;                                       \
        float d00 = xn ? vB0.x : vB0.w;                                        \
        float d01 = xn ? vB0.y : vB1.x;                                        \
        float d02 = xn ? vB0.z : vB1.y;                                        \
        float w00 = (vx0 & vy0) ? (1.0f - wx) * (1.0f - wy) : 0.0f;            \
        float w01 = (vx1 & vy0) ? wx * (1.0f - wy)          : 0.0f;            \
        float w10 = (vx0 & vy1) ? (1.0f - wx) * wy          : 0.0f;            \
        float w11 = (vx1 & vy1) ? wx * wy                   : 0.0f;            \
        A0 = a00*w00 + b00*w01 + c00*w10 + d00*w11;                            \
        A1 = a01*w00 + b01*w01 + c01*w10 + d01*w11;                            \
        A2 = a02*w00 + b02*w01 + c02*w10 + d02*w11;                            \
    } while (0)

    float o0a, o1a, o2a, o0b, o1b, o2b;
    SAMPLE(tid,        o0a, o1a, o2a);
    SAMPLE(tid + 256,  o0b, o1b, o2b);
    #undef SAMPLE

    // stage through LDS for coalesced, vectorized stores
    s_out[tid*3 + 0] = o0a;
    s_out[tid*3 + 1] = o1a;
    s_out[tid*3 + 2] = o2a;
    s_out[(tid + 256)*3 + 0] = o0b;
    s_out[(tid + 256)*3 + 1] = o1b;
    s_out[(tid + 256)*3 + 2] = o2b;
    __syncthreads();

    // 512 px * 3 ch = 1536 floats = 384 float4 per row
    f32x4* outp = reinterpret_cast<f32x4*>(
        out + ((unsigned)(b * IMG_H + y)) * (IMG_W * IMG_C));
    f32x4 v0 = *reinterpret_cast<const f32x4*>(&s_out[tid * 4]);
    __builtin_nontemporal_store(v0, &outp[tid]);
    if (tid < 128) {
        f32x4 v1 = *reinterpret_cast<const f32x4*>(&s_out[(256 + tid) * 4]);
        __builtin_nontemporal_store(v1, &outp[256 + tid]);
    }
}

extern "C" void kernel_launch(void* const* d_in, const int* in_sizes, int n_in,
                              void* d_out, int out_size, void* d_ws, size_t ws_size,
                              hipStream_t stream) {
    const float* images = (const float*)d_in[0];
    const float* focal  = (const float*)d_in[1];
    const float* q      = (const float*)d_in[2];
    float* out = (float*)d_out;

    dim3 grid(16384);   // H * B = 512 * 32 rows, one row per block
    dim3 block(256);
    warp_kernel<<<grid, block, 0, stream>>>(images, focal, q, out);
}

// Round 8
// 33.549 us; speedup vs baseline: 1.0064x; 1.0064x over previous
//
#include <hip/hip_runtime.h>
#include <hip/hip_bf16.h>

// ResidualRotationWarpLayer: out[b,y,x,c] = bilinear(images[b], H_b warp of (x,y))
// H_b = diag(fx,fy,1) * R(q) * diag(fx,fy,1)^-1
// B=32, H=512, W=512, C=3, fp32.
//
// R8: VALU cut. Fast v_rcp_f32 instead of full-precision divide (error
// ~1e-4 px, tolerance 0.0156). Wave-uniform interior fast path (__all):
// no clamps/masks, 6-float pair loads per corner row. Edge waves take the
// scalar clamped path. XCD swizzle + LDS-staged NT stores unchanged.

#define IMG_H 512
#define IMG_W 512
#define IMG_C 3
#define NB    32

typedef float f32x4  __attribute__((ext_vector_type(4)));
typedef float f32x4u __attribute__((ext_vector_type(4), aligned(4)));
typedef float f32x2u __attribute__((ext_vector_type(2), aligned(4)));

__global__ __launch_bounds__(256) void warp_kernel(
    const float* __restrict__ images,
    const float* __restrict__ focal,
    const float* __restrict__ q,
    float* __restrict__ out)
{
    // --- XCD-aware remap: 16384 blocks = 8 XCDs * 2048; each XCD owns 4 images
    const unsigned bid  = blockIdx.x;
    const unsigned xcd  = bid & 7u;
    const unsigned slot = bid >> 3;
    const unsigned virt = xcd * 2048u + slot;
    const int b = (int)(virt >> 9);      // 512 rows per image
    const int y = (int)(virt & 511u);

    const int tid = threadIdx.x;

    __shared__ float sH[9];
    __shared__ float s_out[IMG_W * IMG_C];   // 1536 floats = 6 KB

    if (tid == 0) {
        // replicate reference op order for numerics
        float q0 = q[0], q1 = q[1], q2 = q[2], q3 = q[3];
        float s = sqrtf(2.0f / (q0*q0 + q1*q1 + q2*q2 + q3*q3));
        q0 *= s; q1 *= s; q2 *= s; q3 *= s;
        float R00 = 1.0f - q2*q2 - q3*q3;
        float R01 = q1*q2 - q3*q0;
        float R02 = q1*q3 + q2*q0;
        float R10 = q1*q2 + q3*q0;
        float R11 = 1.0f - q1*q1 - q3*q3;
        float R12 = q2*q3 - q1*q0;
        float R20 = q1*q3 - q2*q0;
        float R21 = q2*q3 + q1*q0;
        float R22 = 1.0f - q1*q1 - q2*q2;
        float d0 = focal[b*2 + 0];
        float d1 = focal[b*2 + 1];
        sH[0] = (R00*d0)/d0; sH[1] = (R01*d0)/d1; sH[2] = (R02*d0);
        sH[3] = (R10*d1)/d0; sH[4] = (R11*d1)/d1; sH[5] = (R12*d1);
        sH[6] = R20/d0;      sH[7] = R21/d1;      sH[8] = R22;
    }
    __syncthreads();

    const float h0 = sH[0], h3 = sH[3], h6 = sH[6];

    const float ys = (float)y - 256.0f;
    // row-constant parts of the projective transform
    const float r1 = sH[1]*ys + sH[2];
    const float r4 = sH[4]*ys + sH[5];
    const float r7 = sH[7]*ys + sH[8];

    const float* __restrict__ img_b = images + (unsigned)b * (IMG_H * IMG_W * IMG_C);

    #define SAMPLE(PX, A0, A1, A2) do {                                        \
        const float xs = (float)(PX) - 256.0f;                                 \
        float p0 = fmaf(h0, xs, r1);                                           \
        float p1 = fmaf(h3, xs, r4);                                           \
        float p2 = fmaf(h6, xs, r7);                                           \
        float rp2 = __builtin_amdgcn_rcpf(p2);                                 \
        float xw = fmaf(p0, rp2, 256.0f);                                      \
        float yw = fmaf(p1, rp2, 256.0f);                                      \
        float x0f = floorf(xw), y0f = floorf(yw);                              \
        float wx = xw - x0f,   wy = yw - y0f;                                  \
        int x0 = (int)x0f, y0i = (int)y0f;                                     \
        bool interior = (x0 >= 0) & (y0i >= 0) &                               \
                        (x0 < IMG_W-1) & (y0i < IMG_H-1);                      \
        if (__all(interior)) {                                                 \
            /* fast path: no clamps/masks; 6-float pair load per corner row */ \
            const float* bpA = img_b + ((unsigned)y0i * IMG_W + (unsigned)x0) * 3u; \
            const float* bpB = bpA + IMG_W * 3u;                               \
            f32x4u vA0 = *reinterpret_cast<const f32x4u*>(bpA);                \
            f32x2u vA1 = *reinterpret_cast<const f32x2u*>(bpA + 4);            \
            f32x4u vB0 = *reinterpret_cast<const f32x4u*>(bpB);                \
            f32x2u vB1 = *reinterpret_cast<const f32x2u*>(bpB + 4);            \
            float w00 = (1.0f - wx) * (1.0f - wy);                             \
            float w01 = wx * (1.0f - wy);                                      \
            float w10 = (1.0f - wx) * wy;                                      \
            float w11 = wx * wy;                                               \
            A0 = vA0.x*w00 + vA0.w*w01 + vB0.x*w10 + vB0.w*w11;                \
            A1 = vA0.y*w00 + vA1.x*w01 + vB0.y*w10 + vB1.x*w11;                \
            A2 = vA0.z*w00 + vA1.y*w01 + vB0.z*w10 + vB1.y*w11;                \
        } else {                                                               \
            /* slow path: scalar clamped loads, masked weights (R6) */         \
            int x1 = x0 + 1, y1i = y0i + 1;                                    \
            bool vx0 = (x0 >= 0) & (x0 <= IMG_W-1);                            \
            bool vx1 = (x1 >= 0) & (x1 <= IMG_W-1);                            \
            bool vy0 = (y0i >= 0) & (y0i <= IMG_H-1);                          \
            bool vy1 = (y1i >= 0) & (y1i <= IMG_H-1);                          \
            unsigned xc0 = (unsigned)min(max(x0, 0), IMG_W-1);                 \
            unsigned xc1 = (unsigned)min(max(x1, 0), IMG_W-1);                 \
            unsigned yc0 = (unsigned)min(max(y0i, 0), IMG_H-1);                \
            unsigned yc1 = (unsigned)min(max(y1i, 0), IMG_H-1);                \
            const float* p00 = img_b + (yc0 * IMG_W + xc0) * IMG_C;            \
            const float* p01 = img_b + (yc0 * IMG_W + xc1) * IMG_C;            \
            const float* p10 = img_b + (yc1 * IMG_W + xc0) * IMG_C;            \
            const float* p11 = img_b + (yc1 * IMG_W + xc1) * IMG_C;            \
            float a00 = p00[0], a01 = p00[1], a02 = p00[2];                    \
            float b00 = p01[0], b01 = p01[1], b02 = p01[2];                    \
            float c00 = p10[0], c01 = p10[1], c02 = p10[2];                    \
            float d00 = p11[0], d01 = p11[1], d02 = p11[2];                    \
            float w00 = (vx0 & vy0) ? (1.0f - wx) * (1.0f - wy) : 0.0f;        \
            float w01 = (vx1 & vy0) ? wx * (1.0f - wy)          : 0.0f;        \
            float w10 = (vx0 & vy1) ? (1.0f - wx) * wy          : 0.0f;        \
            float w11 = (vx1 & vy1) ? wx * wy                   : 0.0f;        \
            A0 = a00*w00 + b00*w01 + c00*w10 + d00*w11;                        \
            A1 = a01*w00 + b01*w01 + c01*w10 + d01*w11;                        \
            A2 = a02*w00 + b02*w01 + c02*w10 + d02*w11;                        \
        }                                                                      \
    } while (0)

    float o0a, o1a, o2a, o0b, o1b, o2b;
    SAMPLE(tid,        o0a, o1a, o2a);
    SAMPLE(tid + 256,  o0b, o1b, o2b);
    #undef SAMPLE

    // stage through LDS for coalesced, vectorized stores
    s_out[tid*3 + 0] = o0a;
    s_out[tid*3 + 1] = o1a;
    s_out[tid*3 + 2] = o2a;
    s_out[(tid + 256)*3 + 0] = o0b;
    s_out[(tid + 256)*3 + 1] = o1b;
    s_out[(tid + 256)*3 + 2] = o2b;
    __syncthreads();

    // 512 px * 3 ch = 1536 floats = 384 float4 per row
    f32x4* outp = reinterpret_cast<f32x4*>(
        out + ((unsigned)(b * IMG_H + y)) * (IMG_W * IMG_C));
    f32x4 v0 = *reinterpret_cast<const f32x4*>(&s_out[tid * 4]);
    __builtin_nontemporal_store(v0, &outp[tid]);
    if (tid < 128) {
        f32x4 v1 = *reinterpret_cast<const f32x4*>(&s_out[(256 + tid) * 4]);
        __builtin_nontemporal_store(v1, &outp[256 + tid]);
    }
}

extern "C" void kernel_launch(void* const* d_in, const int* in_sizes, int n_in,
                              void* d_out, int out_size, void* d_ws, size_t ws_size,
                              hipStream_t stream) {
    const float* images = (const float*)d_in[0];
    const float* focal  = (const float*)d_in[1];
    const float* q      = (const float*)d_in[2];
    float* out = (float*)d_out;

    dim3 grid(16384);   // H * B = 512 * 32 rows, one row per block
    dim3 block(256);
    warp_kernel<<<grid, block, 0, stream>>>(images, focal, q, out);
}